// Round 1
// baseline (4996.445 us; speedup 1.0000x reference)
//
#include <hip/hip_runtime.h>
#include <math.h>

#define LOG2E 1.4426950408889634f
#define LN2   0.6931471805599453f

typedef short  short8  __attribute__((ext_vector_type(8)));
typedef float  floatx4 __attribute__((ext_vector_type(4)));

__constant__ int c_pi[28] = {0,0,0,0,0,0,0,1,1,1,1,1,1,2,2,2,2,2,3,3,3,3,4,4,4,5,5,6};
__constant__ int c_pj[28] = {1,2,3,4,5,6,7,2,3,4,5,6,7,3,4,5,6,7,4,5,6,7,5,6,7,6,7,7};

// ---------------- static device storage (no d_ws dependence) ----------------
__device__ unsigned short g_cellsL[16*256*256];   // bf16 bits, gathered local cells
__device__ unsigned short g_cellsG[8*512*256];    // bf16 bits, gathered global cells
__device__ float g_x2L[16*256];
__device__ float g_x2G[8*512];
__device__ int   g_idxL[16*256];
__device__ int   g_idxG[8*512];
__device__ float g_CxyL[56*256*256];              // 14.68 MB
__device__ float g_CxxL[16*256*256];              //  4.19 MB
__device__ float g_CxyG[28*512*512];              // 29.36 MB
__device__ float g_CxxG[8*512*512];               //  8.39 MB
__device__ float g_fL[2][56*256];
__device__ float g_gL[2][56*256];
__device__ float g_pxL[2][16*256];
__device__ float g_fG[2][28*512];
__device__ float g_gG[2][28*512];
__device__ float g_pxG[2][8*512];

// ---------------- helpers ----------------
__device__ __forceinline__ unsigned short f2bf(float f) {
    unsigned u = __float_as_uint(f);
    u += 0x7fffu + ((u >> 16) & 1u);          // RNE; inputs are finite
    return (unsigned short)(u >> 16);
}

// ---------------- index lists: first-m matches in order (ballot scan) -------
__global__ void k_index(const int* __restrict__ labels, const int* __restrict__ subg) {
    int b = blockIdx.x, lane = threadIdx.x;   // 24 blocks x 64 threads
    int want_l, want_s, cap; int* out;
    if (b < 16) { want_l = b >> 3; want_s = b & 7; cap = 256; out = g_idxL + b*256; }
    else        { want_l = -1;     want_s = b - 16; cap = 512; out = g_idxG + (b-16)*512; }
    int cnt = 0;
    for (int base = 0; base < 4096; base += 64) {
        int i = base + lane;
        bool m = (subg[i] == want_s) && (want_l < 0 || labels[i] == want_l);
        unsigned long long mask = __ballot(m);
        int pos = cnt + __popcll(mask & ((1ull << lane) - 1ull));
        if (m && pos < cap) out[pos] = i;
        cnt += __popcll(mask);
    }
}

// ---------------- gather rows -> bf16 cells + fp32 sq-norms -----------------
__global__ void k_gather(const float* __restrict__ feat) {
    int wv = blockIdx.x*4 + (threadIdx.x >> 6);   // 8192 waves, one row each
    int lane = threadIdx.x & 63;
    const float* src; unsigned short* dst; float* x2out;
    if (wv < 4096) {
        int c = wv >> 8, row = wv & 255;
        src = feat + (size_t)g_idxL[c*256+row]*256;
        dst = g_cellsL + (size_t)(c*256+row)*256;
        x2out = g_x2L + c*256 + row;
    } else {
        int v = wv - 4096; int c = v >> 9, row = v & 511;
        src = feat + (size_t)g_idxG[c*512+row]*256;
        dst = g_cellsG + (size_t)(c*512+row)*256;
        x2out = g_x2G + c*512 + row;
    }
    floatx4 v4 = *(const floatx4*)(src + lane*4);
    float s = v4[0]*v4[0] + v4[1]*v4[1] + v4[2]*v4[2] + v4[3]*v4[3];
    unsigned lo = (unsigned)f2bf(v4[0]) | ((unsigned)f2bf(v4[1]) << 16);
    unsigned hi = (unsigned)f2bf(v4[2]) | ((unsigned)f2bf(v4[3]) << 16);
    unsigned* d32 = (unsigned*)dst;
    d32[lane*2] = lo; d32[lane*2+1] = hi;
    for (int o = 32; o; o >>= 1) s += __shfl_xor(s, o);
    if (lane == 0) *x2out = s;
}

// ---------------- cost matrices via bf16 MFMA (wave = one 16x16 tile) -------
// C_ij = 0.5*max(x2_i + y2_j - 2*x.y, 0)
__global__ void k_gemm() {
    int job = blockIdx.x*4 + (threadIdx.x >> 6);
    int lane = threadIdx.x & 63;
    const unsigned short *A, *B; float* Cout; const float *x2a, *x2b;
    int m, ti, tj;
    if (job < 14336) {                      // local Cxy: 56 pairs x 256 tiles
        int p = job >> 8, t = job & 255; ti = t >> 4; tj = t & 15; m = 256;
        int lbl = p / 28, q = p % 28;
        int ca = lbl*8 + c_pi[q], cb = lbl*8 + c_pj[q];
        A = g_cellsL + (size_t)ca*65536; B = g_cellsL + (size_t)cb*65536;
        x2a = g_x2L + ca*256; x2b = g_x2L + cb*256;
        Cout = g_CxyL + (size_t)p*65536;
    } else if (job < 18432) {               // local Cxx: 16 cells x 256 tiles
        int jj = job - 14336; int c = jj >> 8, t = jj & 255; ti = t >> 4; tj = t & 15; m = 256;
        A = B = g_cellsL + (size_t)c*65536; x2a = x2b = g_x2L + c*256;
        Cout = g_CxxL + (size_t)c*65536;
    } else if (job < 47104) {               // global Cxy: 28 pairs x 1024 tiles
        int jj = job - 18432; int p = jj >> 10, t = jj & 1023; ti = t >> 5; tj = t & 31; m = 512;
        A = g_cellsG + (size_t)c_pi[p]*131072; B = g_cellsG + (size_t)c_pj[p]*131072;
        x2a = g_x2G + c_pi[p]*512; x2b = g_x2G + c_pj[p]*512;
        Cout = g_CxyG + (size_t)p*262144;
    } else {                                // global Cxx: 8 cells x 1024 tiles
        int jj = job - 47104; int c = jj >> 10, t = jj & 1023; ti = t >> 5; tj = t & 31; m = 512;
        A = B = g_cellsG + (size_t)c*131072; x2a = x2b = g_x2G + c*512;
        Cout = g_CxxG + (size_t)c*262144;
    }
    int r = lane & 15, quad = lane >> 4;
    // verified layout: A/B frag = mat[lane&15][quad*8 + j] (row-major, 8 contiguous k)
    const unsigned short* Ap = A + (size_t)(ti*16 + r)*256 + quad*8;
    const unsigned short* Bp = B + (size_t)(tj*16 + r)*256 + quad*8;
    floatx4 acc = {0.f, 0.f, 0.f, 0.f};
    #pragma unroll
    for (int k = 0; k < 256; k += 32) {
        short8 av = *(const short8*)(Ap + k);
        short8 bv = *(const short8*)(Bp + k);
        acc = __builtin_amdgcn_mfma_f32_16x16x32_bf16(av, bv, acc, 0, 0, 0);
    }
    int jc = tj*16 + r;                     // D: col = lane&15, row = quad*4 + reg
    float y2 = x2b[jc];
    #pragma unroll
    for (int rr = 0; rr < 4; rr++) {
        int ir = ti*16 + quad*4 + rr;
        float v = x2a[ir] + y2 - 2.f*acc[rr];
        Cout[(size_t)ir*m + jc] = 0.5f*fmaxf(v, 0.f);
    }
}

// ---------------- zero the parity-0 potential buffers -----------------------
__global__ void k_init() {
    int t = blockIdx.x*256 + threadIdx.x;   // 65536 threads
    if      (t < 14336) g_fL[0][t] = 0.f;
    else if (t < 28672) g_gL[0][t-14336] = 0.f;
    else if (t < 32768) g_pxL[0][t-28672] = 0.f;
    else if (t < 47104) g_fG[0][t-32768] = 0.f;
    else if (t < 61440) g_gG[0][t-47104] = 0.f;
    else                g_pxG[0][t-61440] = 0.f;
}

// ---------------- softmin row pass: ft_i = -eps*LSE_j(h_j - C_ij/eps) -------
template<int M>
__device__ __forceinline__ void sm_row(const float* __restrict__ C,
    const float* __restrict__ hsrc, const float* __restrict__ fold,
    float* __restrict__ fout, int r0, float eps, float inv_eps, float loga,
    int hard, int fin, float* hbuf)
{
    const int CH = M/64;
    int tid = threadIdx.x;
    for (int j = tid; j < M; j += 256) hbuf[j] = loga + hsrc[j]*inv_eps;
    __syncthreads();
    int lane = tid & 63, w = tid >> 6;
    for (int rr = 0; rr < 16; rr++) {
        int row = r0 + w*16 + rr;
        const float* cr = C + (size_t)row*M;
        float t[CH]; float mx = -3.4e38f;
        #pragma unroll
        for (int s = 0; s < CH; s++) {
            float tv = hbuf[lane + 64*s] - cr[lane + 64*s]*inv_eps;
            t[s] = tv; mx = fmaxf(mx, tv);
        }
        for (int o = 32; o; o >>= 1) mx = fmaxf(mx, __shfl_xor(mx, o));
        float ft;
        if (!hard) {
            float sum = 0.f;
            #pragma unroll
            for (int s = 0; s < CH; s++) sum += exp2f((t[s]-mx)*LOG2E);
            for (int o = 32; o; o >>= 1) sum += __shfl_xor(sum, o);
            ft = -eps*(mx + LN2*__log2f(sum));
        } else {
            ft = -eps*mx;                   // |err| <= eps*ln(M), negligible for eps<1e-5
        }
        if (lane == 0) fout[row] = fin ? ft : 0.5f*(fold[row] + ft);
    }
}

// ---------------- softmin col pass (Cyx = Cxy^T without transpose) ----------
template<int M>
__device__ __forceinline__ void sm_col(const float* __restrict__ C,
    const float* __restrict__ hsrc, const float* __restrict__ gold,
    float* __restrict__ gout, int j0, float eps, float inv_eps, float loga,
    int hard, int fin, float* hbuf, float* sred)
{
    const int RPT = M/4;
    int tid = threadIdx.x;
    for (int i = tid; i < M; i += 256) hbuf[i] = loga + hsrc[i]*inv_eps;
    __syncthreads();
    int lane = tid & 63, q = tid >> 6;
    const float* cb = C + (size_t)(q*RPT)*M + j0 + lane;
    float mx = -3.4e38f;
    #pragma unroll 4
    for (int s = 0; s < RPT; s++) {
        float tv = hbuf[q*RPT + s] - cb[(size_t)s*M]*inv_eps;
        mx = fmaxf(mx, tv);
    }
    sred[q*64 + lane] = mx;
    __syncthreads();
    float cm = fmaxf(fmaxf(sred[lane], sred[64+lane]), fmaxf(sred[128+lane], sred[192+lane]));
    if (!hard) {
        __syncthreads();                    // protect sred reuse
        float sum = 0.f;
        #pragma unroll 4
        for (int s = 0; s < RPT; s++) {
            float tv = hbuf[q*RPT + s] - cb[(size_t)s*M]*inv_eps;
            sum += exp2f((tv - cm)*LOG2E);
        }
        sred[q*64 + lane] = sum;
        __syncthreads();
        if (tid < 64) {
            float tot = sred[tid] + sred[64+tid] + sred[128+tid] + sred[192+tid];
            float gt = -eps*(cm + LN2*__log2f(tot));
            gout[j0+tid] = fin ? gt : 0.5f*(gold[j0+tid] + gt);
        }
    } else {
        if (tid < 64) {
            float gt = -eps*cm;
            gout[j0+tid] = fin ? gt : 0.5f*(gold[j0+tid] + gt);
        }
    }
}

// ---------------- one eps-scaling iteration (all 84 units + 24 cells) -------
// blocks: [0,224) Lrow | [224,448) Lcol | [448,512) Lcell |
//         [512,736) Grow | [736,960) Gcol | [960,1024) Gcell
__global__ void k_iter(float eps, float inv_eps, int par, int hard, int fin) {
    __shared__ float hbuf[512];
    __shared__ float sred[256];
    const float LGA = -5.545177444479562f;  // -ln 256
    const float LGG = -6.238324625039508f;  // -ln 512
    int b = blockIdx.x;
    int po = par, pn = par ^ 1;
    if (b < 224) {
        int p = b >> 2, rb = (b & 3)*64;
        sm_row<256>(g_CxyL + (size_t)p*65536, g_gL[po]+p*256, g_fL[po]+p*256, g_fL[pn]+p*256,
                    rb, eps, inv_eps, LGA, hard, fin, hbuf);
    } else if (b < 448) {
        int bb = b - 224; int p = bb >> 2, cb = (bb & 3)*64;
        sm_col<256>(g_CxyL + (size_t)p*65536, g_fL[po]+p*256, g_gL[po]+p*256, g_gL[pn]+p*256,
                    cb, eps, inv_eps, LGA, hard, fin, hbuf, sred);
    } else if (b < 512) {
        int bb = b - 448; int c = bb >> 2, rb = (bb & 3)*64;
        sm_row<256>(g_CxxL + (size_t)c*65536, g_pxL[po]+c*256, g_pxL[po]+c*256, g_pxL[pn]+c*256,
                    rb, eps, inv_eps, LGA, hard, fin, hbuf);
    } else if (b < 736) {
        int bb = b - 512; int p = bb >> 3, rb = (bb & 7)*64;
        sm_row<512>(g_CxyG + (size_t)p*262144, g_gG[po]+p*512, g_fG[po]+p*512, g_fG[pn]+p*512,
                    rb, eps, inv_eps, LGG, hard, fin, hbuf);
    } else if (b < 960) {
        int bb = b - 736; int p = bb >> 3, cb = (bb & 7)*64;
        sm_col<512>(g_CxyG + (size_t)p*262144, g_fG[po]+p*512, g_gG[po]+p*512, g_gG[pn]+p*512,
                    cb, eps, inv_eps, LGG, hard, fin, hbuf, sred);
    } else {
        int bb = b - 960; int c = bb >> 3, rb = (bb & 7)*64;
        sm_row<512>(g_CxxG + (size_t)c*262144, g_pxG[po]+c*512, g_pxG[po]+c*512, g_pxG[pn]+c*512,
                    rb, eps, inv_eps, LGG, hard, fin, hbuf);
    }
}

// ---------------- final reduction to the scalar loss ------------------------
// local = S_L/(56*256) - P_L/(8*256);  global = S_G/(28*512) - P_G/(4*512)
__global__ void k_combine(float* __restrict__ out) {
    __shared__ float red[4][4];
    int tid = threadIdx.x;                  // 256 threads
    float sfg_l = 0.f, spx_l = 0.f, sfg_g = 0.f, spx_g = 0.f;
    for (int i = tid; i < 14336; i += 256) sfg_l += g_fL[1][i] + g_gL[1][i];
    for (int i = tid; i < 4096;  i += 256) spx_l += g_pxL[1][i];
    for (int i = tid; i < 14336; i += 256) sfg_g += g_fG[1][i] + g_gG[1][i];
    for (int i = tid; i < 4096;  i += 256) spx_g += g_pxG[1][i];
    for (int o = 32; o; o >>= 1) {
        sfg_l += __shfl_xor(sfg_l, o); spx_l += __shfl_xor(spx_l, o);
        sfg_g += __shfl_xor(sfg_g, o); spx_g += __shfl_xor(spx_g, o);
    }
    int w = tid >> 6;
    if ((tid & 63) == 0) { red[0][w] = sfg_l; red[1][w] = spx_l; red[2][w] = sfg_g; red[3][w] = spx_g; }
    __syncthreads();
    if (tid == 0) {
        float SL = red[0][0]+red[0][1]+red[0][2]+red[0][3];
        float PL = red[1][0]+red[1][1]+red[1][2]+red[1][3];
        float SG = red[2][0]+red[2][1]+red[2][2]+red[2][3];
        float PG = red[3][0]+red[3][1]+red[3][2]+red[3][3];
        float local_l  = SL/14336.f - PL/2048.f;
        float global_l = SG/14336.f - PG/2048.f;
        out[0] = 1.0f*local_l + 0.5f*global_l;
    }
}

// ---------------- host launcher ---------------------------------------------
extern "C" void kernel_launch(void* const* d_in, const int* in_sizes, int n_in,
                              void* d_out, int out_size, void* d_ws, size_t ws_size,
                              hipStream_t stream) {
    (void)in_sizes; (void)n_in; (void)out_size; (void)d_ws; (void)ws_size;
    const float* feat  = (const float*)d_in[0];
    const int* labels  = (const int*)d_in[1];
    const int* subg    = (const int*)d_in[2];

    k_index <<<24,    64, 0, stream>>>(labels, subg);
    k_gather<<<2048, 256, 0, stream>>>(feat);
    k_gemm  <<<13824,256, 0, stream>>>();
    k_init  <<<256,  256, 0, stream>>>();

    // eps schedule identical to reference (double, like numpy)
    double eps0 = 4.0*256.0, ratio = 0.9*0.9, target = 1e-4*1e-4;
    int n = (int)ceil(log(target/eps0)/log(ratio));    // 121 -> 122 iterations
    float ef = 1e-8f;
    for (int k = 0; k <= n; k++) {
        double e = eps0 * pow(ratio, (double)k);
        if (e < target) e = target;
        ef = (float)e;
        int hard = (ef < 1e-5f) ? 1 : 0;
        k_iter<<<1024, 256, 0, stream>>>(ef, (float)(1.0/(double)ef), k & 1, hard, 0);
    }
    // final extrapolation at eps_f (reads parity 0 carry, writes raw to parity 1)
    k_iter<<<1024, 256, 0, stream>>>(ef, (float)(1.0/(double)ef), 0, 1, 1);
    k_combine<<<1, 256, 0, stream>>>((float*)d_out);
}

// Round 2
// 2018.715 us; speedup vs baseline: 2.4751x; 2.4751x over previous
//
#include <hip/hip_runtime.h>
#include <math.h>

#define LOG2E 1.4426950408889634f
#define LN2   0.6931471805599453f

typedef short    short8  __attribute__((ext_vector_type(8)));
typedef float    floatx4 __attribute__((ext_vector_type(4)));
typedef _Float16 half8   __attribute__((ext_vector_type(8)));

__constant__ int c_pi[28] = {0,0,0,0,0,0,0,1,1,1,1,1,1,2,2,2,2,2,3,3,3,3,4,4,4,5,5,6};
__constant__ int c_pj[28] = {1,2,3,4,5,6,7,2,3,4,5,6,7,3,4,5,6,7,4,5,6,7,5,6,7,6,7,7};

// ---------------- static device storage ----------------
__device__ unsigned short g_cellsL[16*256*256];   // bf16 bits, gathered local cells
__device__ unsigned short g_cellsG[8*512*256];    // bf16 bits, gathered global cells
__device__ float g_x2L[16*256];
__device__ float g_x2G[8*512];
__device__ int   g_idxL[16*256];
__device__ int   g_idxG[8*512];
// fp16 cost matrices. Local: [0,56)=Cxy, [56,112)=Cyx(T), [112,128)=Cxx. 16.8 MB
__device__ _Float16 g_CL[128*256*256];
// Global: [0,28)=Cxy, [28,56)=Cyx(T), [56,64)=Cxx. 33.6 MB
__device__ _Float16 g_CG[64*512*512];
__device__ float g_fL[2][56*256];
__device__ float g_gL[2][56*256];
__device__ float g_pxL[2][16*256];
__device__ float g_fG[2][28*512];
__device__ float g_gG[2][28*512];
__device__ float g_pxG[2][8*512];

// ---------------- helpers ----------------
__device__ __forceinline__ unsigned short f2bf(float f) {
    unsigned u = __float_as_uint(f);
    u += 0x7fffu + ((u >> 16) & 1u);          // RNE; inputs are finite
    return (unsigned short)(u >> 16);
}

// ---------------- index lists: first-m matches in order (ballot scan) -------
__global__ void k_index(const int* __restrict__ labels, const int* __restrict__ subg) {
    int b = blockIdx.x, lane = threadIdx.x;   // 24 blocks x 64 threads
    int want_l, want_s, cap; int* out;
    if (b < 16) { want_l = b >> 3; want_s = b & 7; cap = 256; out = g_idxL + b*256; }
    else        { want_l = -1;     want_s = b - 16; cap = 512; out = g_idxG + (b-16)*512; }
    int cnt = 0;
    for (int base = 0; base < 4096; base += 64) {
        int i = base + lane;
        bool m = (subg[i] == want_s) && (want_l < 0 || labels[i] == want_l);
        unsigned long long mask = __ballot(m);
        int pos = cnt + __popcll(mask & ((1ull << lane) - 1ull));
        if (m && pos < cap) out[pos] = i;
        cnt += __popcll(mask);
    }
}

// ---------------- gather rows -> bf16 cells + fp32 sq-norms -----------------
__global__ void k_gather(const float* __restrict__ feat) {
    int wv = blockIdx.x*4 + (threadIdx.x >> 6);   // 8192 waves, one row each
    int lane = threadIdx.x & 63;
    const float* src; unsigned short* dst; float* x2out;
    if (wv < 4096) {
        int c = wv >> 8, row = wv & 255;
        src = feat + (size_t)g_idxL[c*256+row]*256;
        dst = g_cellsL + (size_t)(c*256+row)*256;
        x2out = g_x2L + c*256 + row;
    } else {
        int v = wv - 4096; int c = v >> 9, row = v & 511;
        src = feat + (size_t)g_idxG[c*512+row]*256;
        dst = g_cellsG + (size_t)(c*512+row)*256;
        x2out = g_x2G + c*512 + row;
    }
    floatx4 v4 = *(const floatx4*)(src + lane*4);
    float s = v4[0]*v4[0] + v4[1]*v4[1] + v4[2]*v4[2] + v4[3]*v4[3];
    unsigned lo = (unsigned)f2bf(v4[0]) | ((unsigned)f2bf(v4[1]) << 16);
    unsigned hi = (unsigned)f2bf(v4[2]) | ((unsigned)f2bf(v4[3]) << 16);
    unsigned* d32 = (unsigned*)dst;
    d32[lane*2] = lo; d32[lane*2+1] = hi;
    for (int o = 32; o; o >>= 1) s += __shfl_xor(s, o);
    if (lane == 0) *x2out = s;
}

// ---------------- cost matrices via bf16 MFMA (wave = one 16x16 tile) -------
// C_ij = 0.5*max(x2_i + y2_j - 2*x.y, 0), stored fp16. T matrices are built as
// an independent GEMM with A/B swapped (coalesced writes, no transpose pass).
__global__ void k_gemm() {
    int job = blockIdx.x*4 + (threadIdx.x >> 6);
    int lane = threadIdx.x & 63;
    const unsigned short *A, *B; _Float16* Cout; const float *x2a, *x2b;
    int m, ti, tj;
    if (job < 32768) {                      // local: 128 matrices x 256 tiles
        int mm = job >> 8, t = job & 255; ti = t >> 4; tj = t & 15; m = 256;
        int ca, cb;
        if (mm < 56)       { int lbl = mm/28,  q = mm%28;  ca = lbl*8 + c_pi[q]; cb = lbl*8 + c_pj[q]; }
        else if (mm < 112) { int p = mm-56; int lbl = p/28, q = p%28;
                             ca = lbl*8 + c_pj[q]; cb = lbl*8 + c_pi[q]; }
        else               { int c = mm-112; ca = cb = c; }
        A = g_cellsL + (size_t)ca*65536; B = g_cellsL + (size_t)cb*65536;
        x2a = g_x2L + ca*256; x2b = g_x2L + cb*256;
        Cout = g_CL + (size_t)mm*65536;
    } else {                                // global: 64 matrices x 1024 tiles
        int jj = job - 32768; int mm = jj >> 10, t = jj & 1023; ti = t >> 5; tj = t & 31; m = 512;
        int ca, cb;
        if (mm < 28)      { ca = c_pi[mm];    cb = c_pj[mm]; }
        else if (mm < 56) { ca = c_pj[mm-28]; cb = c_pi[mm-28]; }
        else              { ca = cb = mm-56; }
        A = g_cellsG + (size_t)ca*131072; B = g_cellsG + (size_t)cb*131072;
        x2a = g_x2G + ca*512; x2b = g_x2G + cb*512;
        Cout = g_CG + (size_t)mm*262144;
    }
    int r = lane & 15, quad = lane >> 4;
    // verified layout: A/B frag = mat[lane&15][quad*8 + j] (row-major, 8 contiguous k)
    const unsigned short* Ap = A + (size_t)(ti*16 + r)*256 + quad*8;
    const unsigned short* Bp = B + (size_t)(tj*16 + r)*256 + quad*8;
    floatx4 acc = {0.f, 0.f, 0.f, 0.f};
    #pragma unroll
    for (int k = 0; k < 256; k += 32) {
        short8 av = *(const short8*)(Ap + k);
        short8 bv = *(const short8*)(Bp + k);
        acc = __builtin_amdgcn_mfma_f32_16x16x32_bf16(av, bv, acc, 0, 0, 0);
    }
    int jc = tj*16 + r;                     // D: col = lane&15, row = quad*4 + reg
    float y2 = x2b[jc];
    #pragma unroll
    for (int rr = 0; rr < 4; rr++) {
        int ir = ti*16 + quad*4 + rr;
        float v = x2a[ir] + y2 - 2.f*acc[rr];
        Cout[(size_t)ir*m + jc] = (_Float16)(0.5f*fmaxf(v, 0.f));
    }
}

// ---------------- zero the parity-0 potential buffers -----------------------
__global__ void k_init() {
    int t = blockIdx.x*256 + threadIdx.x;   // 65536 threads
    if      (t < 14336) g_fL[0][t] = 0.f;
    else if (t < 28672) g_gL[0][t-14336] = 0.f;
    else if (t < 32768) g_pxL[0][t-28672] = 0.f;
    else if (t < 47104) g_fG[0][t-32768] = 0.f;
    else if (t < 61440) g_gG[0][t-47104] = 0.f;
    else                g_pxG[0][t-61440] = 0.f;
}

// ---------------- row softmin pass, fully register-resident -----------------
// ft_i = -eps*LSE_j(h_j - C_ij/eps); every pass is a row pass (T materialized).
// M=256: half-wave per row (lanes 0-31 / 32-63), 16 rows/wave, stripe = 64 rows.
// M=512: full wave per row, 8 rows/wave, stripe = 32 rows.
template<int M>
__device__ __forceinline__ void sm_pass(const _Float16* __restrict__ C,
    const float* __restrict__ hsrc, const float* __restrict__ fold,
    float* __restrict__ fout, int r0, float eps, float inv_eps, float loga,
    int hard, int fin)
{
    const int W = (M == 256) ? 16 : 32;     // shfl butterfly start
    int tid = threadIdx.x, lane = tid & 63, w = tid >> 6;
    int co = (M == 256) ? (lane & 31) : lane;
    float h[8];
    floatx4 h0 = *(const floatx4*)(hsrc + co*8);
    floatx4 h1 = *(const floatx4*)(hsrc + co*8 + 4);
    #pragma unroll
    for (int k = 0; k < 4; k++) { h[k] = loga + h0[k]*inv_eps; h[4+k] = loga + h1[k]*inv_eps; }
    int rbase = (M == 256) ? (r0 + w*16) : (r0 + w*8);
    int rowst = (M == 256) ? 2 : 1;
    int radd  = (M == 256) ? (lane >> 5) : 0;
    bool wr   = (M == 256) ? ((lane & 31) == 0) : (lane == 0);

    const _Float16* cp = C + (size_t)(rbase + radd)*M + co*8;
    half8 cv = *(const half8*)cp;           // 2-stage pipeline: prefetch next row
    #pragma unroll
    for (int s = 0; s < 8; s++) {
        half8 cvn;
        if (s < 7) cvn = *(const half8*)(cp + (size_t)rowst*M);
        float tv[8]; float mx = -3.4e38f;
        #pragma unroll
        for (int k = 0; k < 8; k++) {
            float t = h[k] - (float)cv[k]*inv_eps;
            tv[k] = t; mx = fmaxf(mx, t);
        }
        #pragma unroll
        for (int o = W; o; o >>= 1) mx = fmaxf(mx, __shfl_xor(mx, o));
        float ft;
        if (!hard) {
            float sum = 0.f;
            #pragma unroll
            for (int k = 0; k < 8; k++) sum += exp2f((tv[k] - mx)*LOG2E);
            #pragma unroll
            for (int o = W; o; o >>= 1) sum += __shfl_xor(sum, o);
            ft = -eps*(mx + LN2*__log2f(sum));
        } else {
            ft = -eps*mx;                   // |err| <= eps*ln(M), negligible for eps<1e-5
        }
        if (wr) {
            int row = rbase + rowst*s + radd;
            fout[row] = fin ? ft : 0.5f*(fold[row] + ft);
        }
        cv = cvn; cp += (size_t)rowst*M;
    }
}

// ---------------- one eps-scaling iteration (208 matrix-passes) -------------
// blocks [0,512): local (128 matrices x 4 stripes of 64 rows)
// blocks [512,1536): global (64 matrices x 16 stripes of 32 rows)
__global__ void k_iter(float eps, float inv_eps, int par, int hard, int fin) {
    const float LGA = -5.545177444479562f;  // -ln 256
    const float LGG = -6.238324625039508f;  // -ln 512
    int b = blockIdx.x;
    int po = par, pn = par ^ 1;
    if (b < 512) {
        int m = b >> 2, r0 = (b & 3)*64;
        const _Float16* C = g_CL + (size_t)m*65536;
        const float *h, *fo; float* fn;
        if (m < 56)       { h = g_gL[po]+m*256;  fo = g_fL[po]+m*256;  fn = g_fL[pn]+m*256; }
        else if (m < 112) { int p = m-56;  h = g_fL[po]+p*256;  fo = g_gL[po]+p*256;  fn = g_gL[pn]+p*256; }
        else              { int c = m-112; h = g_pxL[po]+c*256; fo = h;               fn = g_pxL[pn]+c*256; }
        sm_pass<256>(C, h, fo, fn, r0, eps, inv_eps, LGA, hard, fin);
    } else {
        int v = b - 512; int m = v >> 4, r0 = (v & 15)*32;
        const _Float16* C = g_CG + (size_t)m*262144;
        const float *h, *fo; float* fn;
        if (m < 28)      { h = g_gG[po]+m*512;  fo = g_fG[po]+m*512;  fn = g_fG[pn]+m*512; }
        else if (m < 56) { int p = m-28;  h = g_fG[po]+p*512;  fo = g_gG[po]+p*512;  fn = g_gG[pn]+p*512; }
        else             { int c = m-56;  h = g_pxG[po]+c*512; fo = h;               fn = g_pxG[pn]+c*512; }
        sm_pass<512>(C, h, fo, fn, r0, eps, inv_eps, LGG, hard, fin);
    }
}

// ---------------- final reduction to the scalar loss ------------------------
__global__ void k_combine(float* __restrict__ out) {
    __shared__ float red[4][4];
    int tid = threadIdx.x;                  // 256 threads
    float sfg_l = 0.f, spx_l = 0.f, sfg_g = 0.f, spx_g = 0.f;
    for (int i = tid; i < 14336; i += 256) sfg_l += g_fL[1][i] + g_gL[1][i];
    for (int i = tid; i < 4096;  i += 256) spx_l += g_pxL[1][i];
    for (int i = tid; i < 14336; i += 256) sfg_g += g_fG[1][i] + g_gG[1][i];
    for (int i = tid; i < 4096;  i += 256) spx_g += g_pxG[1][i];
    for (int o = 32; o; o >>= 1) {
        sfg_l += __shfl_xor(sfg_l, o); spx_l += __shfl_xor(spx_l, o);
        sfg_g += __shfl_xor(sfg_g, o); spx_g += __shfl_xor(spx_g, o);
    }
    int w = tid >> 6;
    if ((tid & 63) == 0) { red[0][w] = sfg_l; red[1][w] = spx_l; red[2][w] = sfg_g; red[3][w] = spx_g; }
    __syncthreads();
    if (tid == 0) {
        float SL = red[0][0]+red[0][1]+red[0][2]+red[0][3];
        float PL = red[1][0]+red[1][1]+red[1][2]+red[1][3];
        float SG = red[2][0]+red[2][1]+red[2][2]+red[2][3];
        float PG = red[3][0]+red[3][1]+red[3][2]+red[3][3];
        float local_l  = SL/14336.f - PL/2048.f;
        float global_l = SG/14336.f - PG/2048.f;
        out[0] = 1.0f*local_l + 0.5f*global_l;
    }
}

// ---------------- host launcher ---------------------------------------------
extern "C" void kernel_launch(void* const* d_in, const int* in_sizes, int n_in,
                              void* d_out, int out_size, void* d_ws, size_t ws_size,
                              hipStream_t stream) {
    (void)in_sizes; (void)n_in; (void)out_size; (void)d_ws; (void)ws_size;
    const float* feat  = (const float*)d_in[0];
    const int* labels  = (const int*)d_in[1];
    const int* subg    = (const int*)d_in[2];

    k_index <<<24,    64, 0, stream>>>(labels, subg);
    k_gather<<<2048, 256, 0, stream>>>(feat);
    k_gemm  <<<24576,256, 0, stream>>>();
    k_init  <<<256,  256, 0, stream>>>();

    // eps schedule identical to reference (double, like numpy)
    double eps0 = 4.0*256.0, ratio = 0.9*0.9, target = 1e-4*1e-4;
    int n = (int)ceil(log(target/eps0)/log(ratio));    // 121 -> 122 iterations
    float ef = 1e-8f;
    for (int k = 0; k <= n; k++) {
        double e = eps0 * pow(ratio, (double)k);
        if (e < target) e = target;
        ef = (float)e;
        int hard = (ef < 1e-5f) ? 1 : 0;
        k_iter<<<1536, 256, 0, stream>>>(ef, (float)(1.0/(double)ef), k & 1, hard, 0);
    }
    // final extrapolation at eps_f (reads parity 0 carry, writes raw to parity 1)
    k_iter<<<1536, 256, 0, stream>>>(ef, (float)(1.0/(double)ef), 0, 1, 1);
    k_combine<<<1, 256, 0, stream>>>((float*)d_out);
}